// Round 12
// baseline (85.959 us; speedup 1.0000x reference)
//
#include <hip/hip_runtime.h>

// Chamfer loss: x [B,N,D], y [B,M,D], D=3, fp32.
// dist[b,m,n] = ||x[b,n]-y[b,m]||^2
// row[b] = mean_n min_m dist ; col[b] = mean_m min_n dist
// out = mean_b max(row, col)
//
// R12 = R11 (symmetric fusion: each distance computed once, serves both
// directions via c = h_x + h_y - x.y, dist = 2c) + packed-point loads.
//  K0: pack x,y as float4 (px,py,pz, 0.5*||p||^2)  [2 MB].
//  K1: 2048 blocks (32 batch x 64 y-chunks) x 128 thr, QPT=16. Queries now
//      load as 16 coalesced dwordx4 (was 48 stride-12B scattered dwords +
//      ~100 VALU of h recompute per thread, repeated x64 blocks/batch).
//      Row partials -> part; complete col-mins -> colmin (padded LDS tree).
//  K2: 256 row-combine blocks + 32 col-sum blocks -> blocksums.
//  K3: 1 block x 64: per-batch means -> max(row,col) -> mean -> out.

#define BATCH   32
#define NPTS    2048
#define THREADS 128
#define QPT     16             // 128*16 = 2048 x-queries per block
#define TCH     64             // y-chunks per batch
#define TC      (NPTS / TCH)   // 32 y-targets per chunk
#define NROWB   (BATCH * 8)    // 256 row-combine blocks
#define NCOLB   BATCH          // 32 col-sum blocks
#define NPTSTOT (2 * BATCH * NPTS)   // 131072 packed points

// packed layout: [0 .. B*NPTS) = x points, [B*NPTS .. 2*B*NPTS) = y points
__global__ __launch_bounds__(256) void chamfer_pack(
    const float* __restrict__ x, const float* __restrict__ y,
    float4* __restrict__ packed)
{
    const int gid = blockIdx.x * 256 + threadIdx.x;   // 0..131071
    const int half = gid >> 16;          // 0: x, 1: y
    const int idx  = gid & 0xFFFF;
    const float* src = (half == 0 ? x : y);
    float px = src[3 * idx + 0];
    float py = src[3 * idx + 1];
    float pz = src[3 * idx + 2];
    packed[gid] = make_float4(px, py, pz, 0.5f * (px * px + py * py + pz * pz));
}

__global__ __launch_bounds__(THREADS, 4) void chamfer_min(
    const float4* __restrict__ packed,
    float* __restrict__ part    /* [BATCH][TCH][NPTS] */,
    float* __restrict__ colmin  /* [BATCH][NPTS] */)
{
    __shared__ float4 t4[TC];                 // (ty0,ty1,ty2, h_y) — 512 B
    __shared__ float colLds[THREADS][TC + 1]; // +1 pad: conflict-free — 16.9 KB
    __shared__ float cmPart[4][TC + 1];       // 528 B

    const int blk   = blockIdx.x;      // 2048
    const int b     = blk >> 6;
    const int chunk = blk & 63;

    const float4* qp = packed + (size_t)b * NPTS;                    // x points
    const float4* tp = packed + (size_t)BATCH * NPTS + (size_t)b * NPTS; // y

    // Stage this chunk's 32 y-targets (already packed with h_y).
    if (threadIdx.x < TC)
        t4[threadIdx.x] = tp[chunk * TC + threadIdx.x];

    // 16 x-queries per thread: coalesced float4 loads.
    float nqx[QPT], nqy[QPT], nqz[QPT], hx[QPT], mn[QPT];
#pragma unroll
    for (int k = 0; k < QPT; ++k) {
        float4 qv = qp[threadIdx.x + k * THREADS];
        nqx[k] = -qv.x;
        nqy[k] = -qv.y;
        nqz[k] = -qv.z;
        hx[k]  = qv.w;
        mn[k]  = 3.4e38f;
    }
    __syncthreads();

    // c(n,m) = h_x + h_y - x.y ; dist = 2c. Row-min in regs, col-partial to LDS.
#pragma unroll 2
    for (int j = 0; j < TC; j += 2) {
        float4 a  = t4[j];                // wave-uniform -> broadcast
        float4 c4 = t4[j + 1];
        float colA = 3.4e38f, colB = 3.4e38f;
#pragma unroll
        for (int k = 0; k < QPT; k += 2) {
            float Wa0 = a.w  + hx[k],     Wb0 = c4.w + hx[k];
            float Wa1 = a.w  + hx[k + 1], Wb1 = c4.w + hx[k + 1];
            float s0 = fmaf(nqz[k], a.z, fmaf(nqy[k], a.y, fmaf(nqx[k], a.x, Wa0)));
            float s1 = fmaf(nqz[k], c4.z, fmaf(nqy[k], c4.y, fmaf(nqx[k], c4.x, Wb0)));
            float t0 = fmaf(nqz[k+1], a.z, fmaf(nqy[k+1], a.y, fmaf(nqx[k+1], a.x, Wa1)));
            float t1 = fmaf(nqz[k+1], c4.z, fmaf(nqy[k+1], c4.y, fmaf(nqx[k+1], c4.x, Wb1)));
            mn[k]     = fminf(fminf(mn[k], s0), s1);       // v_min3
            mn[k + 1] = fminf(fminf(mn[k + 1], t0), t1);   // v_min3
            colA = fminf(fminf(colA, s0), t0);             // v_min3
            colB = fminf(fminf(colB, s1), t1);             // v_min3
        }
        colLds[threadIdx.x][j]     = colA;
        colLds[threadIdx.x][j + 1] = colB;
    }
    __syncthreads();

    // Col reduce: 4 groups of 32 rows, one (group, target) per thread.
    {
        const int g = threadIdx.x >> 5;    // 0..3
        const int j = threadIdx.x & 31;    // target within chunk
        float cp = 3.4e38f;
#pragma unroll
        for (int i = 0; i < 32; ++i)
            cp = fminf(cp, colLds[g * 32 + i][j]);
        cmPart[g][j] = cp;
    }
    __syncthreads();
    if (threadIdx.x < TC) {
        const int j = threadIdx.x;
        float cm = fminf(fminf(cmPart[0][j], cmPart[1][j]),
                         fminf(cmPart[2][j], cmPart[3][j]));
        colmin[(size_t)b * NPTS + chunk * TC + j] = cm;   // complete col-min
    }

    // Row partials: plain coalesced writes — no init, no atomics.
    float* pbase = part + ((size_t)b * TCH + chunk) * NPTS;
#pragma unroll
    for (int k = 0; k < QPT; ++k)
        pbase[threadIdx.x + k * THREADS] = mn[k];
}

#define CTHREADS 256

__global__ __launch_bounds__(CTHREADS) void chamfer_combine(
    const float* __restrict__ part,
    const float* __restrict__ colmin,
    float* __restrict__ blocksums /* [NROWB + NCOLB] */)
{
    __shared__ float wsum[CTHREADS / 64];

    const int blk = blockIdx.x;        // 288 = NROWB + NCOLB
    float d;

    if (blk < NROWB) {
        // Row: min over 64 chunks for one query, d = 2c.
        const int b  = blk >> 3;
        const int qc = blk & 7;
        const int qi = qc * CTHREADS + threadIdx.x;
        const float* p = part + (size_t)b * TCH * NPTS + qi;
        float mn = p[0];
#pragma unroll
        for (int c = 1; c < TCH; ++c)
            mn = fminf(mn, p[(size_t)c * NPTS]);
        d = 2.0f * mn;
    } else {
        // Col: sum 2*colmin over this batch (8 values per thread).
        const int b = blk - NROWB;
        const float* p = colmin + (size_t)b * NPTS;
        float s = 0.0f;
#pragma unroll
        for (int i = 0; i < 8; ++i)
            s += p[threadIdx.x + i * CTHREADS];
        d = 2.0f * s;
    }

    for (int off = 32; off > 0; off >>= 1)
        d += __shfl_down(d, off);
    if ((threadIdx.x & 63) == 0) wsum[threadIdx.x >> 6] = d;
    __syncthreads();
    if (threadIdx.x == 0)
        blocksums[blk] = wsum[0] + wsum[1] + wsum[2] + wsum[3];
}

__global__ void chamfer_finalize(const float* __restrict__ blocksums,
                                 float* __restrict__ out)
{
    const int lane = threadIdx.x;   // 64 threads; lanes >= 32 contribute 0
    float v = 0.0f;
    if (lane < BATCH) {
        float rs = 0.0f;
#pragma unroll
        for (int i = 0; i < 8; ++i)
            rs += blocksums[lane * 8 + i];
        float cs = blocksums[NROWB + lane];
        v = fmaxf(rs, cs) * (1.0f / NPTS);
    }
    for (int off = 32; off > 0; off >>= 1)
        v += __shfl_down(v, off);
    if (lane == 0) out[0] = v * (1.0f / BATCH);
}

extern "C" void kernel_launch(void* const* d_in, const int* in_sizes, int n_in,
                              void* d_out, int out_size, void* d_ws, size_t ws_size,
                              hipStream_t stream) {
    const float* x = (const float*)d_in[0];
    const float* y = (const float*)d_in[1];
    float* out = (float*)d_out;

    float*  part      = (float*)d_ws;                          // 16 MB
    float*  colmin    = part + (size_t)BATCH * TCH * NPTS;     // 256 KB
    float*  blocksums = colmin + (size_t)BATCH * NPTS;         // ~1.2 KB
    float4* packed    = (float4*)(blocksums + 512);            // 2 MB

    chamfer_pack<<<NPTSTOT / 256, 256, 0, stream>>>(x, y, packed);
    chamfer_min<<<BATCH * TCH, THREADS, 0, stream>>>(packed, part, colmin);
    chamfer_combine<<<NROWB + NCOLB, CTHREADS, 0, stream>>>(part, colmin, blocksums);
    chamfer_finalize<<<1, 64, 0, stream>>>(blocksums, out);
}